// Round 10
// baseline (203.876 us; speedup 1.0000x reference)
//
#include <hip/hip_runtime.h>

typedef __attribute__((ext_vector_type(8))) short short8;
typedef __attribute__((ext_vector_type(4))) float f32x4;

#define S_    2048
#define DI    1024
#define DQK   512
#define DV    512
#define NTOK  8192   // 4 * 2048

// async global->LDS DMA, 16 B/lane (global_load_lds_dwordx4)
#define GLL(gp, lp) __builtin_amdgcn_global_load_lds( \
    (const __attribute__((address_space(1))) unsigned int*)(gp), \
    (__attribute__((address_space(3))) unsigned int*)(lp), 16, 0, 0)

static __device__ __forceinline__ unsigned short f2bf(float f) {
  unsigned int u = __float_as_uint(f);
  u += 0x7fffu + ((u >> 16) & 1u);          // RNE
  return (unsigned short)(u >> 16);
}

// ---------- W transpose-convert; also zeroes the rowsum buffer ----------
// (x conversion folded into qkv -- this kernel is now tiny, ~1.5 us)
__global__ void conv_w_kernel(const float* __restrict__ W0, const float* __restrict__ W1,
                              const float* __restrict__ W2,
                              unsigned short* __restrict__ T0, unsigned short* __restrict__ T1,
                              unsigned short* __restrict__ T2,
                              float* __restrict__ rowsum) {
  __shared__ float tile[32][33];
  int mat = blockIdx.z;
  if (mat == 0 && blockIdx.x == 0)
    rowsum[blockIdx.y * 256 + threadIdx.x] = 0.f;   // 32*256 = 8192 rows
  const float* W = (mat == 0) ? W0 : (mat == 1) ? W1 : W2;
  unsigned short* T = (mat == 0) ? T0 : (mat == 1) ? T1 : T2;
  int n0 = blockIdx.x * 32, k0 = blockIdx.y * 32;
  int c = threadIdx.x & 31, r0 = threadIdx.x >> 5;
  for (int i = 0; i < 4; ++i) {
    int kk = r0 + i * 8;
    tile[kk][c] = W[(k0 + kk) * DQK + n0 + c];
  }
  __syncthreads();
  for (int i = 0; i < 4; ++i) {
    int nn = r0 + i * 8;
    T[(n0 + nn) * DI + k0 + c] = f2bf(tile[c][nn]);
  }
}

// ---------- 128x128 GEMM-BT core, NSTAGE-deep, counted vmcnt (for s_exp)
// Validated rounds 4..9. Hazard audit in round-4 notes. Source-side chunk
// swizzle (m173) -> 4-way ds_read conflict.
template<int NSTAGE>
__device__ __forceinline__ void gemm_core_128x128(
    const unsigned short* __restrict__ A, const unsigned short* __restrict__ B,
    int lda, int ldb, int K, int m0, int n0,
    unsigned short* As, unsigned short* Bs, f32x4 (&acc)[4][4]) {
  int tid = threadIdx.x, lane = tid & 63, wv = tid >> 6;
  int quad = lane >> 4, l16 = lane & 15;
  int wm = wv >> 1, wn = wv & 1;
  int r0 = wv * 32 + (lane >> 2);
  int c8 = ((lane & 3) ^ ((lane >> 2) & 3)) * 8;   // swizzled source chunk
  const unsigned short* ga0 = A + (size_t)(m0 + r0) * lda + c8;
  const unsigned short* ga1 = ga0 + (size_t)16 * lda;   // (r0+16)&3 == r0&3
  const unsigned short* gb0 = B + (size_t)(n0 + r0) * ldb + c8;
  const unsigned short* gb1 = gb0 + (size_t)16 * ldb;
  int ldsw0 = (wv * 32) * 32;          // wave-uniform LDS dests (elements)
  int ldsw1 = ldsw0 + 16 * 32;
#pragma unroll
  for (int i = 0; i < 4; ++i)
#pragma unroll
    for (int j = 0; j < 4; ++j) acc[i][j] = (f32x4){0.f, 0.f, 0.f, 0.f};

  auto stage = [&](int buf, int k0) {
    unsigned short* Ad = As + buf * (128 * 32);
    unsigned short* Bd = Bs + buf * (128 * 32);
    GLL(ga0 + k0, Ad + ldsw0);
    GLL(ga1 + k0, Ad + ldsw1);
    GLL(gb0 + k0, Bd + ldsw0);
    GLL(gb1 + k0, Bd + ldsw1);
  };

  int nk = K >> 5;
  int pc = (quad ^ (l16 & 3)) * 8;     // swizzled read chunk offset
#pragma unroll
  for (int s = 0; s < NSTAGE; ++s) stage(s, s * 32);
  int cur = 0, pre = NSTAGE;           // pre = buffer for tile kt+NSTAGE
  for (int kt = 0; kt < nk; ++kt) {
    if (kt + NSTAGE <= nk) {           // steady: tile kt issued NSTAGE phases ago
      if constexpr (NSTAGE == 2) { asm volatile("s_waitcnt vmcnt(4)" ::: "memory"); }
      else                       { asm volatile("s_waitcnt vmcnt(12)" ::: "memory"); }
    } else {
      asm volatile("s_waitcnt vmcnt(0)" ::: "memory");
    }
    __builtin_amdgcn_sched_barrier(0);
    __builtin_amdgcn_s_barrier();
    __builtin_amdgcn_sched_barrier(0);     // nothing crosses the barrier
    if (kt + NSTAGE < nk) stage(pre, (kt + NSTAGE) * 32);
    __builtin_amdgcn_sched_barrier(0);     // GLL issues stay before reads
    const unsigned short* Ab = As + cur * (128 * 32);
    const unsigned short* Bb = Bs + cur * (128 * 32);
    short8 af[4], bf[4];
#pragma unroll
    for (int t = 0; t < 4; ++t) {
      af[t] = *(const short8*)(Ab + (wm * 64 + t * 16 + l16) * 32 + pc);
      bf[t] = *(const short8*)(Bb + (wn * 64 + t * 16 + l16) * 32 + pc);
    }
#pragma unroll
    for (int tm = 0; tm < 4; ++tm)
#pragma unroll
      for (int tn = 0; tn < 4; ++tn)
        acc[tm][tn] = __builtin_amdgcn_mfma_f32_16x16x32_bf16(af[tm], bf[tn], acc[tm][tn], 0, 0, 0);
    cur = (cur == NSTAGE) ? 0 : cur + 1;
    pre = (pre == NSTAGE) ? 0 : pre + 1;
  }
}

// ---------- QKV projection with FUSED x fp32->bf16 conversion ----------
// Round-10: conv_x kernel deleted. A-path loads x fp32 (float4 x4 per
// wave-step), converts in-register, ds_writes bf16 into a swizzled LDS
// layout (phys_chunk = s ^ ((row>>1)&3); read pcA = (quad^((l16>>1)&3))*8
// -> 2-way (free) read, 4-way write). B-path (W^T) keeps the validated
// GLL source-swizzle. Plain r1 2-phase __syncthreads dbuf (no raw
// barriers): loads/GLLs for step k+1 issue after the barrier (T14
// load-early), A convert+write lands after compute k (write-late);
// __syncthreads drains vmcnt+lgkm -> race-free by construction.
// The 12 blocks sharing an m-stripe are XCD-co-located -> redundant
// fp32 x reads are L2-served (4 MB stripe set per XCD).
__global__ __launch_bounds__(256, 2) void qkv_fused_kernel(
    const float* __restrict__ x,
    const unsigned short* __restrict__ wqt, const unsigned short* __restrict__ wkt,
    const unsigned short* __restrict__ wvt,
    const float* __restrict__ bq, const float* __restrict__ bk, const float* __restrict__ bv,
    unsigned short* __restrict__ qo, unsigned short* __restrict__ ko,
    unsigned short* __restrict__ vto) {
  __shared__ unsigned short As[2][128 * 32];
  __shared__ unsigned short Bs[2][128 * 32];
  int bidx = blockIdx.x;
  int xcd = bidx & 7;
  int local = bidx >> 3;          // [0,96)
  int mlocal = local & 7;
  int col12 = local >> 3;         // [0,12) = mat*4 + ntile
  int mat = col12 >> 2;
  int m0 = (xcd * 8 + mlocal) * 128;
  int n0 = (col12 & 3) * 128;
  const unsigned short* wt = (mat == 0) ? wqt : (mat == 1) ? wkt : wvt;
  const float* bias = (mat == 0) ? bq : (mat == 1) ? bk : bv;
  float oscale = (mat == 0) ? 0.04419417382415922f : 1.0f;  // fold 1/sqrt(512) into q

  int tid = threadIdx.x, lane = tid & 63, wv = tid >> 6;
  int quad = lane >> 4, l16 = lane & 15;
  int wm = wv >> 1, wn = wv & 1;

  // A-path (x fp32): wave covers rows [wv*32, wv*32+32), lane&31 = row,
  // lane>>5 = 4-col half of each 8-col chunk; 4 chunks (s) per step.
  int ra = wv * 32 + (lane & 31);
  int cg = lane >> 5;                         // 0 or 1
  const float* gax = x + (size_t)(m0 + ra) * DI + cg * 4;
  int asw = (ra >> 1) & 3;                    // A chunk swizzle key
  unsigned short* Abase0 = &As[0][ra * 32];
  unsigned short* Abase1 = &As[1][ra * 32];

  // B-path: GLL with source-side chunk swizzle (validated)
  int r0 = wv * 32 + (lane >> 2);
  int c8 = ((lane & 3) ^ ((lane >> 2) & 3)) * 8;
  const unsigned short* gb0 = wt + (size_t)(n0 + r0) * DI + c8;
  const unsigned short* gb1 = gb0 + (size_t)16 * DI;
  int ldsw0 = (wv * 32) * 32;
  int ldsw1 = ldsw0 + 16 * 32;

  f32x4 acc[4][4];
#pragma unroll
  for (int i = 0; i < 4; ++i)
#pragma unroll
    for (int j = 0; j < 4; ++j) acc[i][j] = (f32x4){0.f, 0.f, 0.f, 0.f};

  float4 a0, a1, a2, a3;
  auto loadA = [&](int k0) {
    const float* g = gax + k0;
    a0 = *(const float4*)(g);
    a1 = *(const float4*)(g + 8);
    a2 = *(const float4*)(g + 16);
    a3 = *(const float4*)(g + 24);
  };
  auto writeA = [&](unsigned short* Ad) {
    ushort4 p;
    p.x = f2bf(a0.x); p.y = f2bf(a0.y); p.z = f2bf(a0.z); p.w = f2bf(a0.w);
    *(ushort4*)(Ad + ((0 ^ asw) * 8) + cg * 4) = p;
    p.x = f2bf(a1.x); p.y = f2bf(a1.y); p.z = f2bf(a1.z); p.w = f2bf(a1.w);
    *(ushort4*)(Ad + ((1 ^ asw) * 8) + cg * 4) = p;
    p.x = f2bf(a2.x); p.y = f2bf(a2.y); p.z = f2bf(a2.z); p.w = f2bf(a2.w);
    *(ushort4*)(Ad + ((2 ^ asw) * 8) + cg * 4) = p;
    p.x = f2bf(a3.x); p.y = f2bf(a3.y); p.z = f2bf(a3.z); p.w = f2bf(a3.w);
    *(ushort4*)(Ad + ((3 ^ asw) * 8) + cg * 4) = p;
  };
  auto stageB = [&](int buf, int k0) {
    GLL(gb0 + k0, &Bs[buf][ldsw0]);
    GLL(gb1 + k0, &Bs[buf][ldsw1]);
  };

  loadA(0);
  stageB(0, 0);
  writeA(Abase0);                 // compiler inserts the vmcnt wait for a0..a3
  __syncthreads();                // drains B GLLs + A ds_writes

  int pcA = (quad ^ ((l16 >> 1) & 3)) * 8;
  int pcB = (quad ^ (l16 & 3)) * 8;
  for (int kt = 0; kt < 32; ++kt) {
    int cur = kt & 1;
    if (kt + 1 < 32) { loadA((kt + 1) * 32); stageB(cur ^ 1, (kt + 1) * 32); }
    const unsigned short* Ab = As[cur];
    const unsigned short* Bb = Bs[cur];
    short8 af[4], bf[4];
#pragma unroll
    for (int t = 0; t < 4; ++t) {
      af[t] = *(const short8*)(Ab + (wm * 64 + t * 16 + l16) * 32 + pcA);
      bf[t] = *(const short8*)(Bb + (wn * 64 + t * 16 + l16) * 32 + pcB);
    }
#pragma unroll
    for (int tm = 0; tm < 4; ++tm)
#pragma unroll
      for (int tn = 0; tn < 4; ++tn)
        acc[tm][tn] = __builtin_amdgcn_mfma_f32_16x16x32_bf16(af[tm], bf[tn], acc[tm][tn], 0, 0, 0);
    if (kt + 1 < 32) writeA(cur ? Abase0 : Abase1);   // into buf cur^1
    __syncthreads();
  }

  bool transp = (mat == 2);
  unsigned short* outp = (mat == 0) ? qo : (mat == 1) ? ko : vto;
#pragma unroll
  for (int tn = 0; tn < 4; ++tn) {
    int col = n0 + wn * 64 + tn * 16 + l16;
    float bc = bias[col];
#pragma unroll
    for (int tm = 0; tm < 4; ++tm) {
      int rowb = m0 + wm * 64 + tm * 16 + quad * 4;
      f32x4 a = acc[tm][tn];
      if (!transp) {
        outp[(size_t)(rowb + 0) * DQK + col] = f2bf((a.x + bc) * oscale);
        outp[(size_t)(rowb + 1) * DQK + col] = f2bf((a.y + bc) * oscale);
        outp[(size_t)(rowb + 2) * DQK + col] = f2bf((a.z + bc) * oscale);
        outp[(size_t)(rowb + 3) * DQK + col] = f2bf((a.w + bc) * oscale);
      } else {
        ushort4 pk;
        pk.x = f2bf(a.x + bc); pk.y = f2bf(a.y + bc);
        pk.z = f2bf(a.z + bc); pk.w = f2bf(a.w + bc);
        *(ushort4*)(outp + (size_t)col * NTOK + rowb) = pk;
      }
    }
  }
}

// ---------- S^T = exp(K Q^T): operand-swapped; validated r4 version ------
__global__ __launch_bounds__(256, 2) void s_exp_kernel(
    const unsigned short* __restrict__ q, const unsigned short* __restrict__ k,
    unsigned short* __restrict__ sp, float* __restrict__ rowsum) {
  __shared__ unsigned short As[3 * 128 * 32];
  __shared__ unsigned short Bs[3 * 128 * 32];
  int bidx = blockIdx.x;
  int xcd = bidx & 7, b = xcd >> 1;
  int sub = ((bidx >> 3) << 1) | (xcd & 1);   // [0,256): n fastest within XCD
  int m0 = (sub >> 4) * 128, n0 = (sub & 15) * 128;   // m0 = k-tile, n0 = q-tile
  f32x4 acc[4][4];
  // A = K rows, B = Q rows  ->  acc is S^T fragments (i = k-dim, j = q-dim)
  gemm_core_128x128<2>(k + (size_t)b * S_ * DQK, q + (size_t)b * S_ * DQK,
                       DQK, DQK, DQK, m0, n0, As, Bs, acc);

  int tid = threadIdx.x, lane = tid & 63, wv = tid >> 6;
  int quad = lane >> 4, l16 = lane & 15;
  int wm = wv >> 1, wn = wv & 1;
  unsigned short* Cb = sp + (size_t)b * S_ * S_;
#pragma unroll
  for (int tn = 0; tn < 4; ++tn) {            // q-tiles
    int qrow = n0 + wn * 64 + tn * 16 + l16;
    float rs = 0.f;
#pragma unroll
    for (int tm = 0; tm < 4; ++tm) {          // k-tiles
      int kcol = m0 + wm * 64 + tm * 16 + quad * 4;
      f32x4 a = acc[tm][tn];
      float e0 = __expf(a.x), e1 = __expf(a.y), e2 = __expf(a.z), e3 = __expf(a.w);
      ushort4 pk;
      pk.x = f2bf(e0); pk.y = f2bf(e1); pk.z = f2bf(e2); pk.w = f2bf(e3);
      *(ushort4*)(Cb + (size_t)qrow * S_ + kcol) = pk;
      rs += (e0 + e1) + (e2 + e3);
    }
    rs += __shfl_xor(rs, 16);
    rs += __shfl_xor(rs, 32);                 // sum across the 4 quads
    if (quad == 0) atomicAdd(rowsum + b * S_ + qrow, rs);
  }
}

// ---------- O = (P V) / rowsum: 64x64, BK=64, dbuf + XOR-swizzled LDS ----
// REVERTED to the round-1 structure (best measured pv: 44.9 us). All
// 128^2 / depth-4 / padded variants measured equal-or-worse: pv is
// L3-service-bound on sp+vt traffic; tiling can't fix it (r6-r9).
__global__ __launch_bounds__(256, 4) void pv_kernel(
    const unsigned short* __restrict__ sp, const unsigned short* __restrict__ vt,
    const float* __restrict__ rowsum, float* __restrict__ out) {
  __shared__ unsigned short As[2][64 * 64];   // 8 KB per buffer
  __shared__ unsigned short Bs[2][64 * 64];
  int bidx = blockIdx.x;
  int xcd = bidx & 7, b = xcd >> 1;
  int sub = ((bidx >> 3) << 1) | (xcd & 1);   // [0,256): n fastest within XCD
  int m0 = (sub >> 3) * 64, n0 = (sub & 7) * 64;
  int tid = threadIdx.x, lane = tid & 63, wv = tid >> 6;
  int quad = lane >> 4, l16 = lane & 15;
  int wm = wv >> 1, wn = wv & 1;
  const unsigned short* A = sp + (size_t)b * S_ * S_;
  const unsigned short* B = vt + (size_t)b * S_;          // vt[dim][tok], ld NTOK

  int srow = tid >> 3;
  int schunk = (tid & 7) ^ (srow & 7);
  const unsigned short* gA0 = A + (size_t)(m0 + srow) * S_ + schunk * 8;
  const unsigned short* gA1 = A + (size_t)(m0 + 32 + srow) * S_ + schunk * 8;
  const unsigned short* gB0 = B + (size_t)(n0 + srow) * NTOK + schunk * 8;
  const unsigned short* gB1 = B + (size_t)(n0 + 32 + srow) * NTOK + schunk * 8;
  int ldsw0 = (wv * 8) * 64;          // wave-uniform dests
  int ldsw1 = (32 + wv * 8) * 64;

  f32x4 acc[2][2];
#pragma unroll
  for (int i = 0; i < 2; ++i)
#pragma unroll
    for (int j = 0; j < 2; ++j) acc[i][j] = (f32x4){0.f, 0.f, 0.f, 0.f};

  auto stage = [&](int buf, int k0) {
    GLL(gA0 + k0, &As[buf][ldsw0]);
    GLL(gA1 + k0, &As[buf][ldsw1]);
    GLL(gB0 + k0, &Bs[buf][ldsw0]);
    GLL(gB1 + k0, &Bs[buf][ldsw1]);
  };

  stage(0, 0);
  for (int kt = 0; kt < 32; ++kt) {
    int cur = kt & 1;
    __syncthreads();                       // drains cur's GLLs (issued last iter)
    if (kt + 1 < 32) stage(cur ^ 1, (kt + 1) * 64);
#pragma unroll
    for (int ks = 0; ks < 2; ++ks) {
      int pc = ((ks * 4 + quad) ^ (l16 & 7)) * 8;   // swizzled chunk offset
      short8 af[2], bf[2];
#pragma unroll
      for (int t = 0; t < 2; ++t) {
        af[t] = *(const short8*)(&As[cur][(wm * 32 + t * 16 + l16) * 64 + pc]);
        bf[t] = *(const short8*)(&Bs[cur][(wn * 32 + t * 16 + l16) * 64 + pc]);
      }
#pragma unroll
      for (int tm = 0; tm < 2; ++tm)
#pragma unroll
        for (int tn = 0; tn < 2; ++tn)
          acc[tm][tn] = __builtin_amdgcn_mfma_f32_16x16x32_bf16(af[tm], bf[tn], acc[tm][tn], 0, 0, 0);
    }
  }

  float* ob = out + (size_t)b * S_ * DV;
#pragma unroll
  for (int tm = 0; tm < 2; ++tm) {
    int rowb = m0 + wm * 32 + tm * 16 + quad * 4;
    float inv[4];
#pragma unroll
    for (int i = 0; i < 4; ++i) inv[i] = 1.0f / rowsum[b * S_ + rowb + i];
#pragma unroll
    for (int tn = 0; tn < 2; ++tn) {
      int col = n0 + wn * 32 + tn * 16 + l16;
      f32x4 a = acc[tm][tn];
      ob[(size_t)(rowb + 0) * DV + col] = a.x * inv[0];
      ob[(size_t)(rowb + 1) * DV + col] = a.y * inv[1];
      ob[(size_t)(rowb + 2) * DV + col] = a.z * inv[2];
      ob[(size_t)(rowb + 3) * DV + col] = a.w * inv[3];
    }
  }
}

extern "C" void kernel_launch(void* const* d_in, const int* in_sizes, int n_in,
                              void* d_out, int out_size, void* d_ws, size_t ws_size,
                              hipStream_t stream) {
  const float* x  = (const float*)d_in[0];
  const float* Wq = (const float*)d_in[1];
  const float* bq = (const float*)d_in[2];
  const float* Wk = (const float*)d_in[3];
  const float* bk = (const float*)d_in[4];
  const float* Wv = (const float*)d_in[5];
  const float* bv = (const float*)d_in[6];
  float* out = (float*)d_out;

  char* ws = (char*)d_ws;
  unsigned short* wqt = (unsigned short*)(ws);                         // 1 MB each: W^T bf16
  unsigned short* wkt = (unsigned short*)(ws + 1048576);
  unsigned short* wvt = (unsigned short*)(ws + 2097152);
  unsigned short* qo  = (unsigned short*)(ws + 3145728);               // 8 MB: q bf16 (pre-scaled)
  unsigned short* ko  = (unsigned short*)(ws + 11534336);              // 8 MB: k bf16
  unsigned short* vto = (unsigned short*)(ws + 19922944);              // 8 MB: v^T bf16
  unsigned short* sp  = (unsigned short*)(ws + 28311552);              // 32 MB: e^S bf16
  float* rowsum       = (float*)(ws + 61865984);                       // 32 KB

  dim3 gw(16, 32, 3);
  conv_w_kernel<<<gw, 256, 0, stream>>>(Wq, Wk, Wv, wqt, wkt, wvt, rowsum);
  qkv_fused_kernel<<<768, 256, 0, stream>>>(x, wqt, wkt, wvt, bq, bk, bv, qo, ko, vto);
  s_exp_kernel<<<1024, 256, 0, stream>>>(qo, ko, sp, rowsum);
  pv_kernel<<<1024, 256, 0, stream>>>(sp, vto, rowsum, out);
}

// Round 12
// 192.547 us; speedup vs baseline: 1.0588x; 1.0588x over previous
//
#include <hip/hip_runtime.h>

typedef __attribute__((ext_vector_type(8))) short short8;
typedef __attribute__((ext_vector_type(4))) float f32x4;

#define S_    2048
#define DI    1024
#define DQK   512
#define DV    512
#define NTOK  8192   // 4 * 2048

// async global->LDS DMA, 16 B/lane (global_load_lds_dwordx4)
#define GLL(gp, lp) __builtin_amdgcn_global_load_lds( \
    (const __attribute__((address_space(1))) unsigned int*)(gp), \
    (__attribute__((address_space(3))) unsigned int*)(lp), 16, 0, 0)

static __device__ __forceinline__ unsigned short f2bf(float f) {
  unsigned int u = __float_as_uint(f);
  u += 0x7fffu + ((u >> 16) & 1u);          // RNE
  return (unsigned short)(u >> 16);
}

// ---------- merged conversion kernel: z<3 -> W^T tiles, z>=3 -> x cast ----
__global__ void conv_all_kernel(const float* __restrict__ x,
                                const float* __restrict__ W0, const float* __restrict__ W1,
                                const float* __restrict__ W2,
                                unsigned short* __restrict__ xb,
                                unsigned short* __restrict__ T0, unsigned short* __restrict__ T1,
                                unsigned short* __restrict__ T2,
                                float* __restrict__ rowsum) {
  int z = blockIdx.z;
  if (z >= 3) {
    // x fp32 -> bf16, 8 elems/thread; 8*512=4096 virtual blocks
    int blk = (z - 3) * 512 + blockIdx.y * 16 + blockIdx.x;
    int idx = (blk * 256 + threadIdx.x) * 8;
    const float4* p = (const float4*)(x + idx);
    float4 f0 = p[0], f1 = p[1];
    uint4 o;
    o.x = (unsigned)f2bf(f0.x) | ((unsigned)f2bf(f0.y) << 16);
    o.y = (unsigned)f2bf(f0.z) | ((unsigned)f2bf(f0.w) << 16);
    o.z = (unsigned)f2bf(f1.x) | ((unsigned)f2bf(f1.y) << 16);
    o.w = (unsigned)f2bf(f1.z) | ((unsigned)f2bf(f1.w) << 16);
    *(uint4*)(xb + idx) = o;
    return;
  }
  __shared__ float tile[32][33];
  int mat = z;
  if (mat == 0 && blockIdx.x == 0)
    rowsum[blockIdx.y * 256 + threadIdx.x] = 0.f;   // 32*256 = 8192 rows
  const float* W = (mat == 0) ? W0 : (mat == 1) ? W1 : W2;
  unsigned short* T = (mat == 0) ? T0 : (mat == 1) ? T1 : T2;
  int n0 = blockIdx.x * 32, k0 = blockIdx.y * 32;
  int c = threadIdx.x & 31, r0 = threadIdx.x >> 5;
  for (int i = 0; i < 4; ++i) {
    int kk = r0 + i * 8;
    tile[kk][c] = W[(k0 + kk) * DQK + n0 + c];
  }
  __syncthreads();
  for (int i = 0; i < 4; ++i) {
    int nn = r0 + i * 8;
    T[(n0 + nn) * DI + k0 + c] = f2bf(tile[c][nn]);
  }
}

// ---------- 128x128 GEMM-BT core, NSTAGE-deep, counted vmcnt ----------
// Validated rounds 4/6/7/8/9. Hazard audit in round-4 notes. Source-side
// chunk swizzle (m173) -> 4-way ds_read conflict.
template<int NSTAGE>
__device__ __forceinline__ void gemm_core_128x128(
    const unsigned short* __restrict__ A, const unsigned short* __restrict__ B,
    int lda, int ldb, int K, int m0, int n0,
    unsigned short* As, unsigned short* Bs, f32x4 (&acc)[4][4]) {
  int tid = threadIdx.x, lane = tid & 63, wv = tid >> 6;
  int quad = lane >> 4, l16 = lane & 15;
  int wm = wv >> 1, wn = wv & 1;
  int r0 = wv * 32 + (lane >> 2);
  int c8 = ((lane & 3) ^ ((lane >> 2) & 3)) * 8;   // swizzled source chunk
  const unsigned short* ga0 = A + (size_t)(m0 + r0) * lda + c8;
  const unsigned short* ga1 = ga0 + (size_t)16 * lda;   // (r0+16)&3 == r0&3
  const unsigned short* gb0 = B + (size_t)(n0 + r0) * ldb + c8;
  const unsigned short* gb1 = gb0 + (size_t)16 * ldb;
  int ldsw0 = (wv * 32) * 32;          // wave-uniform LDS dests (elements)
  int ldsw1 = ldsw0 + 16 * 32;
#pragma unroll
  for (int i = 0; i < 4; ++i)
#pragma unroll
    for (int j = 0; j < 4; ++j) acc[i][j] = (f32x4){0.f, 0.f, 0.f, 0.f};

  auto stage = [&](int buf, int k0) {
    unsigned short* Ad = As + buf * (128 * 32);
    unsigned short* Bd = Bs + buf * (128 * 32);
    GLL(ga0 + k0, Ad + ldsw0);
    GLL(ga1 + k0, Ad + ldsw1);
    GLL(gb0 + k0, Bd + ldsw0);
    GLL(gb1 + k0, Bd + ldsw1);
  };

  int nk = K >> 5;
  int pc = (quad ^ (l16 & 3)) * 8;     // swizzled read chunk offset
#pragma unroll
  for (int s = 0; s < NSTAGE; ++s) stage(s, s * 32);
  int cur = 0, pre = NSTAGE;           // pre = buffer for tile kt+NSTAGE
  for (int kt = 0; kt < nk; ++kt) {
    if (kt + NSTAGE <= nk) {           // steady: tile kt issued NSTAGE phases ago
      if constexpr (NSTAGE == 2) { asm volatile("s_waitcnt vmcnt(4)" ::: "memory"); }
      else                       { asm volatile("s_waitcnt vmcnt(12)" ::: "memory"); }
    } else {
      asm volatile("s_waitcnt vmcnt(0)" ::: "memory");
    }
    __builtin_amdgcn_sched_barrier(0);
    __builtin_amdgcn_s_barrier();
    __builtin_amdgcn_sched_barrier(0);     // nothing crosses the barrier
    if (kt + NSTAGE < nk) stage(pre, (kt + NSTAGE) * 32);
    __builtin_amdgcn_sched_barrier(0);     // GLL issues stay before reads
    const unsigned short* Ab = As + cur * (128 * 32);
    const unsigned short* Bb = Bs + cur * (128 * 32);
    short8 af[4], bf[4];
#pragma unroll
    for (int t = 0; t < 4; ++t) {
      af[t] = *(const short8*)(Ab + (wm * 64 + t * 16 + l16) * 32 + pc);
      bf[t] = *(const short8*)(Bb + (wn * 64 + t * 16 + l16) * 32 + pc);
    }
#pragma unroll
    for (int tm = 0; tm < 4; ++tm)
#pragma unroll
      for (int tn = 0; tn < 4; ++tn)
        acc[tm][tn] = __builtin_amdgcn_mfma_f32_16x16x32_bf16(af[tm], bf[tn], acc[tm][tn], 0, 0, 0);
    cur = (cur == NSTAGE) ? 0 : cur + 1;
    pre = (pre == NSTAGE) ? 0 : pre + 1;
  }
}

// ---------- QKV projection, 128x128 tiles, m-stripe -> XCD pinned ----------
__global__ __launch_bounds__(256, 2) void qkv_dma_kernel(
    const unsigned short* __restrict__ xb,
    const unsigned short* __restrict__ wqt, const unsigned short* __restrict__ wkt,
    const unsigned short* __restrict__ wvt,
    const float* __restrict__ bq, const float* __restrict__ bk, const float* __restrict__ bv,
    unsigned short* __restrict__ qo, unsigned short* __restrict__ ko,
    unsigned short* __restrict__ vto) {
  __shared__ unsigned short As[3 * 128 * 32];
  __shared__ unsigned short Bs[3 * 128 * 32];
  int bidx = blockIdx.x;
  int xcd = bidx & 7;
  int local = bidx >> 3;          // [0,96)
  int mlocal = local & 7;
  int col12 = local >> 3;         // [0,12) = mat*4 + ntile
  int mat = col12 >> 2;
  int m0 = (xcd * 8 + mlocal) * 128;
  int n0 = (col12 & 3) * 128;
  const unsigned short* wt = (mat == 0) ? wqt : (mat == 1) ? wkt : wvt;
  const float* bias = (mat == 0) ? bq : (mat == 1) ? bk : bv;
  float oscale = (mat == 0) ? 0.04419417382415922f : 1.0f;  // fold 1/sqrt(512) into q
  f32x4 acc[4][4];
  gemm_core_128x128<2>(xb, wt, DI, DI, DI, m0, n0, As, Bs, acc);

  int tid = threadIdx.x, lane = tid & 63, wv = tid >> 6;
  int quad = lane >> 4, l16 = lane & 15;
  int wm = wv >> 1, wn = wv & 1;
  bool transp = (mat == 2);
  unsigned short* outp = (mat == 0) ? qo : (mat == 1) ? ko : vto;
#pragma unroll
  for (int tn = 0; tn < 4; ++tn) {
    int col = n0 + wn * 64 + tn * 16 + l16;
    float bc = bias[col];
#pragma unroll
    for (int tm = 0; tm < 4; ++tm) {
      int rowb = m0 + wm * 64 + tm * 16 + quad * 4;
      f32x4 a = acc[tm][tn];
      if (!transp) {
        outp[(size_t)(rowb + 0) * DQK + col] = f2bf((a.x + bc) * oscale);
        outp[(size_t)(rowb + 1) * DQK + col] = f2bf((a.y + bc) * oscale);
        outp[(size_t)(rowb + 2) * DQK + col] = f2bf((a.z + bc) * oscale);
        outp[(size_t)(rowb + 3) * DQK + col] = f2bf((a.w + bc) * oscale);
      } else {
        ushort4 pk;
        pk.x = f2bf(a.x + bc); pk.y = f2bf(a.y + bc);
        pk.z = f2bf(a.z + bc); pk.w = f2bf(a.w + bc);
        *(ushort4*)(outp + (size_t)col * NTOK + rowb) = pk;
      }
    }
  }
}

// ---------- S^T = exp(K Q^T), 256x256 tile, K=512 (round-12 change) ----
// Traffic per block (256+256)x512x2 B; 256 blocks -> 134 MB (was 268 at
// 128^2). Per-XCD working set: 4 k-stripes (1 MB) + 8 q-stripes (2 MB)
// = L2-resident, so the 2-phase vmcnt(0) drain is covered by the ~450 cy
// compute+read phase (unlike pv's L3-resident sp). 512 thr = 8 waves
// (2M x 4N), per-wave output 128x64 = acc[8][4], 32 MFMA/wave/step.
// LDS 64 KB dbuf; grid 256 = 1 block/CU. Same r1 2-phase __syncthreads
// schedule, same source-swizzle, same operand-swapped epilogue.
__global__ __launch_bounds__(512, 1) void s_exp_kernel(
    const unsigned short* __restrict__ q, const unsigned short* __restrict__ k,
    unsigned short* __restrict__ sp, float* __restrict__ rowsum) {
  __shared__ unsigned short As[2 * 256 * 32];   // 32 KB
  __shared__ unsigned short Bs[2 * 256 * 32];   // 32 KB
  int bidx = blockIdx.x;
  int xcd = bidx & 7, b = xcd >> 1, p = xcd & 1;
  int local = bidx >> 3;                  // [0,32) per XCD
  int m0 = (p * 4 + (local & 3)) * 256;   // k-tile [0,8)*256
  int n0 = (local >> 2) * 256;            // q-tile [0,8)*256
  const unsigned short* A = k + (size_t)b * S_ * DQK;   // K rows (m-dim)
  const unsigned short* B = q + (size_t)b * S_ * DQK;   // Q rows (n-dim)

  int tid = threadIdx.x, lane = tid & 63, wv = tid >> 6;  // wv in [0,8)
  int quad = lane >> 4, l16 = lane & 15;
  int wm = wv >> 2, wn = wv & 3;          // 2 x 4 wave grid
  int r0 = wv * 32 + (lane >> 2);         // rows 0..255 across 8 waves
  int c8 = ((lane & 3) ^ ((lane >> 2) & 3)) * 8;   // swizzled source chunk
  const unsigned short* ga0 = A + (size_t)(m0 + r0) * DQK + c8;
  const unsigned short* ga1 = ga0 + (size_t)16 * DQK;
  const unsigned short* gb0 = B + (size_t)(n0 + r0) * DQK + c8;
  const unsigned short* gb1 = gb0 + (size_t)16 * DQK;
  int ldsw0 = (wv * 32) * 32;
  int ldsw1 = ldsw0 + 16 * 32;

  f32x4 acc[8][4];
#pragma unroll
  for (int i = 0; i < 8; ++i)
#pragma unroll
    for (int j = 0; j < 4; ++j) acc[i][j] = (f32x4){0.f, 0.f, 0.f, 0.f};

  auto stage = [&](int buf, int k0) {
    GLL(ga0 + k0, As + buf * 8192 + ldsw0);
    GLL(ga1 + k0, As + buf * 8192 + ldsw1);
    GLL(gb0 + k0, Bs + buf * 8192 + ldsw0);
    GLL(gb1 + k0, Bs + buf * 8192 + ldsw1);
  };

  int pc = (quad ^ (l16 & 3)) * 8;        // swizzled read chunk offset
  stage(0, 0);
  for (int kt = 0; kt < 16; ++kt) {       // K=512, BK=32
    int cur = kt & 1;
    __syncthreads();                      // drains cur's GLLs (r1 2-phase)
    if (kt + 1 < 16) stage(cur ^ 1, (kt + 1) * 32);
    const unsigned short* Ab = As + cur * 8192;
    const unsigned short* Bb = Bs + cur * 8192;
    short8 af[8], bf[4];
#pragma unroll
    for (int t = 0; t < 8; ++t)
      af[t] = *(const short8*)(Ab + (wm * 128 + t * 16 + l16) * 32 + pc);
#pragma unroll
    for (int t = 0; t < 4; ++t)
      bf[t] = *(const short8*)(Bb + (wn * 64 + t * 16 + l16) * 32 + pc);
#pragma unroll
    for (int tm = 0; tm < 8; ++tm)
#pragma unroll
      for (int tn = 0; tn < 4; ++tn)
        acc[tm][tn] = __builtin_amdgcn_mfma_f32_16x16x32_bf16(af[tm], bf[tn], acc[tm][tn], 0, 0, 0);
  }

  unsigned short* Cb = sp + (size_t)b * S_ * S_;
#pragma unroll
  for (int tn = 0; tn < 4; ++tn) {            // q-slots
    int qrow = n0 + wn * 64 + tn * 16 + l16;
    float rs = 0.f;
#pragma unroll
    for (int tm = 0; tm < 8; ++tm) {          // k-slots
      int kcol = m0 + wm * 128 + tm * 16 + quad * 4;
      f32x4 a = acc[tm][tn];
      float e0 = __expf(a.x), e1 = __expf(a.y), e2 = __expf(a.z), e3 = __expf(a.w);
      ushort4 pk;
      pk.x = f2bf(e0); pk.y = f2bf(e1); pk.z = f2bf(e2); pk.w = f2bf(e3);
      *(ushort4*)(Cb + (size_t)qrow * S_ + kcol) = pk;
      rs += (e0 + e1) + (e2 + e3);
    }
    rs += __shfl_xor(rs, 16);
    rs += __shfl_xor(rs, 32);                 // sum across the 4 quads
    if (quad == 0) atomicAdd(rowsum + b * S_ + qrow, rs);
  }
}

// ---------- O = (P V) / rowsum: 128x128 tile, K=2048, depth-2 (r7,
// best-measured pv at 43.0 us; 64^2/depth-4/padded all equal-or-worse;
// pv is L3-service-bound on the 33.5 MB sp operand). ----
__global__ __launch_bounds__(256, 2) void pv_kernel(
    const unsigned short* __restrict__ sp, const unsigned short* __restrict__ vt,
    const float* __restrict__ rowsum, float* __restrict__ out) {
  __shared__ unsigned short As[3 * 128 * 32];
  __shared__ unsigned short Bs[3 * 128 * 32];
  int bidx = blockIdx.x;
  int xcd = bidx & 7, b = xcd >> 1;           // 2 XCDs per batch
  int local = bidx >> 3;                      // [0,32) per XCD
  int m0 = (((xcd & 1) << 3) | (local >> 2)) * 128;   // q-tile [0,16)*128
  int n0 = (local & 3) * 128;                 // d-tile [0,4)*128
  f32x4 acc[4][4];
  gemm_core_128x128<2>(sp + (size_t)b * S_ * S_, vt + (size_t)b * S_,
                       S_, NTOK, S_, m0, n0, As, Bs, acc);

  int tid = threadIdx.x, lane = tid & 63, wv = tid >> 6;
  int quad = lane >> 4, l16 = lane & 15;
  int wm = wv >> 1, wn = wv & 1;
  float* ob = out + (size_t)b * S_ * DV;
#pragma unroll
  for (int tm = 0; tm < 4; ++tm) {
    int rowb = m0 + wm * 64 + tm * 16 + quad * 4;
    float inv[4];
#pragma unroll
    for (int i = 0; i < 4; ++i) inv[i] = 1.0f / rowsum[b * S_ + rowb + i];
#pragma unroll
    for (int tn = 0; tn < 4; ++tn) {
      int col = n0 + wn * 64 + tn * 16 + l16;
      f32x4 a = acc[tm][tn];
      ob[(size_t)(rowb + 0) * DV + col] = a.x * inv[0];
      ob[(size_t)(rowb + 1) * DV + col] = a.y * inv[1];
      ob[(size_t)(rowb + 2) * DV + col] = a.z * inv[2];
      ob[(size_t)(rowb + 3) * DV + col] = a.w * inv[3];
    }
  }
}

extern "C" void kernel_launch(void* const* d_in, const int* in_sizes, int n_in,
                              void* d_out, int out_size, void* d_ws, size_t ws_size,
                              hipStream_t stream) {
  const float* x  = (const float*)d_in[0];
  const float* Wq = (const float*)d_in[1];
  const float* bq = (const float*)d_in[2];
  const float* Wk = (const float*)d_in[3];
  const float* bk = (const float*)d_in[4];
  const float* Wv = (const float*)d_in[5];
  const float* bv = (const float*)d_in[6];
  float* out = (float*)d_out;

  char* ws = (char*)d_ws;
  unsigned short* xb  = (unsigned short*)(ws);                         // 16 MB: x bf16
  unsigned short* wqt = (unsigned short*)(ws + 16777216);              // 1 MB each: W^T bf16
  unsigned short* wkt = (unsigned short*)(ws + 16777216 + 1048576);
  unsigned short* wvt = (unsigned short*)(ws + 16777216 + 2097152);
  unsigned short* qo  = (unsigned short*)(ws + 19922944);              // 8 MB: q bf16 (pre-scaled)
  unsigned short* ko  = (unsigned short*)(ws + 19922944 + 8388608);    // 8 MB: k bf16
  unsigned short* vto = (unsigned short*)(ws + 19922944 + 16777216);   // 8 MB: v^T bf16
  unsigned short* sp  = (unsigned short*)(ws + 45088768);              // 32 MB: e^S bf16
  float* rowsum       = (float*)(ws + 45088768 + 33554432);            // 32 KB

  dim3 gc(16, 32, 11);   // z<3: W^T transpose-convert; z>=3: x fp32->bf16
  conv_all_kernel<<<gc, 256, 0, stream>>>(x, Wq, Wk, Wv, xb, wqt, wkt, wvt, rowsum);
  qkv_dma_kernel<<<768, 256, 0, stream>>>(xb, wqt, wkt, wvt, bq, bk, bv, qo, ko, vto);
  s_exp_kernel<<<256, 512, 0, stream>>>(qo, ko, sp, rowsum);
  pv_kernel<<<256, 256, 0, stream>>>(sp, vto, rowsum, out);
}

// Round 13
// 180.863 us; speedup vs baseline: 1.1272x; 1.0646x over previous
//
#include <hip/hip_runtime.h>

typedef __attribute__((ext_vector_type(8))) short short8;
typedef __attribute__((ext_vector_type(4))) float f32x4;

#define S_    2048
#define DI    1024
#define DQK   512
#define DV    512
#define NTOK  8192   // 4 * 2048

// async global->LDS DMA, 16 B/lane (global_load_lds_dwordx4)
#define GLL(gp, lp) __builtin_amdgcn_global_load_lds( \
    (const __attribute__((address_space(1))) unsigned int*)(gp), \
    (__attribute__((address_space(3))) unsigned int*)(lp), 16, 0, 0)

static __device__ __forceinline__ unsigned short f2bf(float f) {
  unsigned int u = __float_as_uint(f);
  u += 0x7fffu + ((u >> 16) & 1u);          // RNE
  return (unsigned short)(u >> 16);
}

// ---------- merged conversion kernel: z<3 -> W^T tiles, z>=3 -> x cast ----
// (validated r4/r6/r7/r8/r12)
__global__ void conv_all_kernel(const float* __restrict__ x,
                                const float* __restrict__ W0, const float* __restrict__ W1,
                                const float* __restrict__ W2,
                                unsigned short* __restrict__ xb,
                                unsigned short* __restrict__ T0, unsigned short* __restrict__ T1,
                                unsigned short* __restrict__ T2,
                                float* __restrict__ rowsum) {
  int z = blockIdx.z;
  if (z >= 3) {
    // x fp32 -> bf16, 8 elems/thread; 8*512=4096 virtual blocks
    int blk = (z - 3) * 512 + blockIdx.y * 16 + blockIdx.x;
    int idx = (blk * 256 + threadIdx.x) * 8;
    const float4* p = (const float4*)(x + idx);
    float4 f0 = p[0], f1 = p[1];
    uint4 o;
    o.x = (unsigned)f2bf(f0.x) | ((unsigned)f2bf(f0.y) << 16);
    o.y = (unsigned)f2bf(f0.z) | ((unsigned)f2bf(f0.w) << 16);
    o.z = (unsigned)f2bf(f1.x) | ((unsigned)f2bf(f1.y) << 16);
    o.w = (unsigned)f2bf(f1.z) | ((unsigned)f2bf(f1.w) << 16);
    *(uint4*)(xb + idx) = o;
    return;
  }
  __shared__ float tile[32][33];
  int mat = z;
  if (mat == 0 && blockIdx.x == 0)
    rowsum[blockIdx.y * 256 + threadIdx.x] = 0.f;   // 32*256 = 8192 rows
  const float* W = (mat == 0) ? W0 : (mat == 1) ? W1 : W2;
  unsigned short* T = (mat == 0) ? T0 : (mat == 1) ? T1 : T2;
  int n0 = blockIdx.x * 32, k0 = blockIdx.y * 32;
  int c = threadIdx.x & 31, r0 = threadIdx.x >> 5;
  for (int i = 0; i < 4; ++i) {
    int kk = r0 + i * 8;
    tile[kk][c] = W[(k0 + kk) * DQK + n0 + c];
  }
  __syncthreads();
  for (int i = 0; i < 4; ++i) {
    int nn = r0 + i * 8;
    T[(n0 + nn) * DI + k0 + c] = f2bf(tile[c][nn]);
  }
}

// ---------- 128x128 GEMM-BT core, NSTAGE-deep, counted vmcnt ----------
// Validated rounds 4/6/7/8/9/12. Hazard audit in round-4 notes.
// Source-side chunk swizzle (m173) -> 4-way ds_read conflict.
template<int NSTAGE>
__device__ __forceinline__ void gemm_core_128x128(
    const unsigned short* __restrict__ A, const unsigned short* __restrict__ B,
    int lda, int ldb, int K, int m0, int n0,
    unsigned short* As, unsigned short* Bs, f32x4 (&acc)[4][4]) {
  int tid = threadIdx.x, lane = tid & 63, wv = tid >> 6;
  int quad = lane >> 4, l16 = lane & 15;
  int wm = wv >> 1, wn = wv & 1;
  int r0 = wv * 32 + (lane >> 2);
  int c8 = ((lane & 3) ^ ((lane >> 2) & 3)) * 8;   // swizzled source chunk
  const unsigned short* ga0 = A + (size_t)(m0 + r0) * lda + c8;
  const unsigned short* ga1 = ga0 + (size_t)16 * lda;   // (r0+16)&3 == r0&3
  const unsigned short* gb0 = B + (size_t)(n0 + r0) * ldb + c8;
  const unsigned short* gb1 = gb0 + (size_t)16 * ldb;
  int ldsw0 = (wv * 32) * 32;          // wave-uniform LDS dests (elements)
  int ldsw1 = ldsw0 + 16 * 32;
#pragma unroll
  for (int i = 0; i < 4; ++i)
#pragma unroll
    for (int j = 0; j < 4; ++j) acc[i][j] = (f32x4){0.f, 0.f, 0.f, 0.f};

  auto stage = [&](int buf, int k0) {
    unsigned short* Ad = As + buf * (128 * 32);
    unsigned short* Bd = Bs + buf * (128 * 32);
    GLL(ga0 + k0, Ad + ldsw0);
    GLL(ga1 + k0, Ad + ldsw1);
    GLL(gb0 + k0, Bd + ldsw0);
    GLL(gb1 + k0, Bd + ldsw1);
  };

  int nk = K >> 5;
  int pc = (quad ^ (l16 & 3)) * 8;     // swizzled read chunk offset
#pragma unroll
  for (int s = 0; s < NSTAGE; ++s) stage(s, s * 32);
  int cur = 0, pre = NSTAGE;           // pre = buffer for tile kt+NSTAGE
  for (int kt = 0; kt < nk; ++kt) {
    if (kt + NSTAGE <= nk) {           // steady: tile kt issued NSTAGE phases ago
      if constexpr (NSTAGE == 2) { asm volatile("s_waitcnt vmcnt(4)" ::: "memory"); }
      else                       { asm volatile("s_waitcnt vmcnt(12)" ::: "memory"); }
    } else {
      asm volatile("s_waitcnt vmcnt(0)" ::: "memory");
    }
    __builtin_amdgcn_sched_barrier(0);
    __builtin_amdgcn_s_barrier();
    __builtin_amdgcn_sched_barrier(0);     // nothing crosses the barrier
    if (kt + NSTAGE < nk) stage(pre, (kt + NSTAGE) * 32);
    __builtin_amdgcn_sched_barrier(0);     // GLL issues stay before reads
    const unsigned short* Ab = As + cur * (128 * 32);
    const unsigned short* Bb = Bs + cur * (128 * 32);
    short8 af[4], bf[4];
#pragma unroll
    for (int t = 0; t < 4; ++t) {
      af[t] = *(const short8*)(Ab + (wm * 64 + t * 16 + l16) * 32 + pc);
      bf[t] = *(const short8*)(Bb + (wn * 64 + t * 16 + l16) * 32 + pc);
    }
#pragma unroll
    for (int tm = 0; tm < 4; ++tm)
#pragma unroll
      for (int tn = 0; tn < 4; ++tn)
        acc[tm][tn] = __builtin_amdgcn_mfma_f32_16x16x32_bf16(af[tm], bf[tn], acc[tm][tn], 0, 0, 0);
    cur = (cur == NSTAGE) ? 0 : cur + 1;
    pre = (pre == NSTAGE) ? 0 : pre + 1;
  }
}

// ---------- QKV projection, 128x128 tiles, m-stripe -> XCD pinned ----------
// (best-measured qkv: sub-41 us since round 1)
__global__ __launch_bounds__(256, 2) void qkv_dma_kernel(
    const unsigned short* __restrict__ xb,
    const unsigned short* __restrict__ wqt, const unsigned short* __restrict__ wkt,
    const unsigned short* __restrict__ wvt,
    const float* __restrict__ bq, const float* __restrict__ bk, const float* __restrict__ bv,
    unsigned short* __restrict__ qo, unsigned short* __restrict__ ko,
    unsigned short* __restrict__ vto) {
  __shared__ unsigned short As[3 * 128 * 32];
  __shared__ unsigned short Bs[3 * 128 * 32];
  int bidx = blockIdx.x;
  int xcd = bidx & 7;
  int local = bidx >> 3;          // [0,96)
  int mlocal = local & 7;
  int col12 = local >> 3;         // [0,12) = mat*4 + ntile
  int mat = col12 >> 2;
  int m0 = (xcd * 8 + mlocal) * 128;
  int n0 = (col12 & 3) * 128;
  const unsigned short* wt = (mat == 0) ? wqt : (mat == 1) ? wkt : wvt;
  const float* bias = (mat == 0) ? bq : (mat == 1) ? bk : bv;
  float oscale = (mat == 0) ? 0.04419417382415922f : 1.0f;  // fold 1/sqrt(512) into q
  f32x4 acc[4][4];
  gemm_core_128x128<2>(xb, wt, DI, DI, DI, m0, n0, As, Bs, acc);

  int tid = threadIdx.x, lane = tid & 63, wv = tid >> 6;
  int quad = lane >> 4, l16 = lane & 15;
  int wm = wv >> 1, wn = wv & 1;
  bool transp = (mat == 2);
  unsigned short* outp = (mat == 0) ? qo : (mat == 1) ? ko : vto;
#pragma unroll
  for (int tn = 0; tn < 4; ++tn) {
    int col = n0 + wn * 64 + tn * 16 + l16;
    float bc = bias[col];
#pragma unroll
    for (int tm = 0; tm < 4; ++tm) {
      int rowb = m0 + wm * 64 + tm * 16 + quad * 4;
      f32x4 a = acc[tm][tn];
      if (!transp) {
        outp[(size_t)(rowb + 0) * DQK + col] = f2bf((a.x + bc) * oscale);
        outp[(size_t)(rowb + 1) * DQK + col] = f2bf((a.y + bc) * oscale);
        outp[(size_t)(rowb + 2) * DQK + col] = f2bf((a.z + bc) * oscale);
        outp[(size_t)(rowb + 3) * DQK + col] = f2bf((a.w + bc) * oscale);
      } else {
        ushort4 pk;
        pk.x = f2bf(a.x + bc); pk.y = f2bf(a.y + bc);
        pk.z = f2bf(a.z + bc); pk.w = f2bf(a.w + bc);
        *(ushort4*)(outp + (size_t)col * NTOK + rowb) = pk;
      }
    }
  }
}

// ---------- S^T = exp(K Q^T), 256x256 tile, K=512 (validated r12) ------
// Halves L2 staging traffic vs 128^2 (134 MB vs 268 MB); per-XCD working
// set (1 MB k + 2 MB q) is L2-resident so the 2-phase drain is covered.
// 512 thr = 8 waves (2M x 4N), acc[8][4]; LDS 64 KB dbuf; grid 256.
__global__ __launch_bounds__(512, 1) void s_exp_kernel(
    const unsigned short* __restrict__ q, const unsigned short* __restrict__ k,
    unsigned short* __restrict__ sp, float* __restrict__ rowsum) {
  __shared__ unsigned short As[2 * 256 * 32];   // 32 KB
  __shared__ unsigned short Bs[2 * 256 * 32];   // 32 KB
  int bidx = blockIdx.x;
  int xcd = bidx & 7, b = xcd >> 1, p = xcd & 1;
  int local = bidx >> 3;                  // [0,32) per XCD
  int m0 = (p * 4 + (local & 3)) * 256;   // k-tile [0,8)*256
  int n0 = (local >> 2) * 256;            // q-tile [0,8)*256
  const unsigned short* A = k + (size_t)b * S_ * DQK;   // K rows (m-dim)
  const unsigned short* B = q + (size_t)b * S_ * DQK;   // Q rows (n-dim)

  int tid = threadIdx.x, lane = tid & 63, wv = tid >> 6;  // wv in [0,8)
  int quad = lane >> 4, l16 = lane & 15;
  int wm = wv >> 2, wn = wv & 3;          // 2 x 4 wave grid
  int r0 = wv * 32 + (lane >> 2);         // rows 0..255 across 8 waves
  int c8 = ((lane & 3) ^ ((lane >> 2) & 3)) * 8;   // swizzled source chunk
  const unsigned short* ga0 = A + (size_t)(m0 + r0) * DQK + c8;
  const unsigned short* ga1 = ga0 + (size_t)16 * DQK;
  const unsigned short* gb0 = B + (size_t)(n0 + r0) * DQK + c8;
  const unsigned short* gb1 = gb0 + (size_t)16 * DQK;
  int ldsw0 = (wv * 32) * 32;
  int ldsw1 = ldsw0 + 16 * 32;

  f32x4 acc[8][4];
#pragma unroll
  for (int i = 0; i < 8; ++i)
#pragma unroll
    for (int j = 0; j < 4; ++j) acc[i][j] = (f32x4){0.f, 0.f, 0.f, 0.f};

  auto stage = [&](int buf, int k0) {
    GLL(ga0 + k0, As + buf * 8192 + ldsw0);
    GLL(ga1 + k0, As + buf * 8192 + ldsw1);
    GLL(gb0 + k0, Bs + buf * 8192 + ldsw0);
    GLL(gb1 + k0, Bs + buf * 8192 + ldsw1);
  };

  int pc = (quad ^ (l16 & 3)) * 8;        // swizzled read chunk offset
  stage(0, 0);
  for (int kt = 0; kt < 16; ++kt) {       // K=512, BK=32
    int cur = kt & 1;
    __syncthreads();                      // drains cur's GLLs (r1 2-phase)
    if (kt + 1 < 16) stage(cur ^ 1, (kt + 1) * 32);
    const unsigned short* Ab = As + cur * 8192;
    const unsigned short* Bb = Bs + cur * 8192;
    short8 af[8], bf[4];
#pragma unroll
    for (int t = 0; t < 8; ++t)
      af[t] = *(const short8*)(Ab + (wm * 128 + t * 16 + l16) * 32 + pc);
#pragma unroll
    for (int t = 0; t < 4; ++t)
      bf[t] = *(const short8*)(Bb + (wn * 64 + t * 16 + l16) * 32 + pc);
#pragma unroll
    for (int tm = 0; tm < 8; ++tm)
#pragma unroll
      for (int tn = 0; tn < 4; ++tn)
        acc[tm][tn] = __builtin_amdgcn_mfma_f32_16x16x32_bf16(af[tm], bf[tn], acc[tm][tn], 0, 0, 0);
  }

  unsigned short* Cb = sp + (size_t)b * S_ * S_;
#pragma unroll
  for (int tn = 0; tn < 4; ++tn) {            // q-slots
    int qrow = n0 + wn * 64 + tn * 16 + l16;
    float rs = 0.f;
#pragma unroll
    for (int tm = 0; tm < 8; ++tm) {          // k-slots
      int kcol = m0 + wm * 128 + tm * 16 + quad * 4;
      f32x4 a = acc[tm][tn];
      float e0 = __expf(a.x), e1 = __expf(a.y), e2 = __expf(a.z), e3 = __expf(a.w);
      ushort4 pk;
      pk.x = f2bf(e0); pk.y = f2bf(e1); pk.z = f2bf(e2); pk.w = f2bf(e3);
      *(ushort4*)(Cb + (size_t)qrow * S_ + kcol) = pk;
      rs += (e0 + e1) + (e2 + e3);
    }
    rs += __shfl_xor(rs, 16);
    rs += __shfl_xor(rs, 32);                 // sum across the 4 quads
    if (quad == 0) atomicAdd(rowsum + b * S_ + qrow, rs);
  }
}

// ---------- O = (P V) / rowsum: 64x64, BK=64, dbuf + XOR-swizzled LDS ----
// BEST-MEASURED pv (r1/r4 structure, sub-42 us, 4 blocks/CU full
// residency). 128^2 (43.0-43.2), tri-buffer (44.9), depth-4 (46),
// padded (51.7) all measured worse: pv is L3-service-bound on sp. ----
__global__ __launch_bounds__(256, 4) void pv_kernel(
    const unsigned short* __restrict__ sp, const unsigned short* __restrict__ vt,
    const float* __restrict__ rowsum, float* __restrict__ out) {
  __shared__ unsigned short As[2][64 * 64];   // 8 KB per buffer
  __shared__ unsigned short Bs[2][64 * 64];
  int bidx = blockIdx.x;
  int xcd = bidx & 7, b = xcd >> 1;
  int sub = ((bidx >> 3) << 1) | (xcd & 1);   // [0,256): n fastest within XCD
  int m0 = (sub >> 3) * 64, n0 = (sub & 7) * 64;
  int tid = threadIdx.x, lane = tid & 63, wv = tid >> 6;
  int quad = lane >> 4, l16 = lane & 15;
  int wm = wv >> 1, wn = wv & 1;
  const unsigned short* A = sp + (size_t)b * S_ * S_;
  const unsigned short* B = vt + (size_t)b * S_;          // vt[dim][tok], ld NTOK

  int srow = tid >> 3;
  int schunk = (tid & 7) ^ (srow & 7);
  const unsigned short* gA0 = A + (size_t)(m0 + srow) * S_ + schunk * 8;
  const unsigned short* gA1 = A + (size_t)(m0 + 32 + srow) * S_ + schunk * 8;
  const unsigned short* gB0 = B + (size_t)(n0 + srow) * NTOK + schunk * 8;
  const unsigned short* gB1 = B + (size_t)(n0 + 32 + srow) * NTOK + schunk * 8;
  int ldsw0 = (wv * 8) * 64;          // wave-uniform dests
  int ldsw1 = (32 + wv * 8) * 64;

  f32x4 acc[2][2];
#pragma unroll
  for (int i = 0; i < 2; ++i)
#pragma unroll
    for (int j = 0; j < 2; ++j) acc[i][j] = (f32x4){0.f, 0.f, 0.f, 0.f};

  auto stage = [&](int buf, int k0) {
    GLL(gA0 + k0, &As[buf][ldsw0]);
    GLL(gA1 + k0, &As[buf][ldsw1]);
    GLL(gB0 + k0, &Bs[buf][ldsw0]);
    GLL(gB1 + k0, &Bs[buf][ldsw1]);
  };

  stage(0, 0);
  for (int kt = 0; kt < 32; ++kt) {
    int cur = kt & 1;
    __syncthreads();                       // drains cur's GLLs (issued last iter)
    if (kt + 1 < 32) stage(cur ^ 1, (kt + 1) * 64);
#pragma unroll
    for (int ks = 0; ks < 2; ++ks) {
      int pc = ((ks * 4 + quad) ^ (l16 & 7)) * 8;   // swizzled chunk offset
      short8 af[2], bf[2];
#pragma unroll
      for (int t = 0; t < 2; ++t) {
        af[t] = *(const short8*)(&As[cur][(wm * 32 + t * 16 + l16) * 64 + pc]);
        bf[t] = *(const short8*)(&Bs[cur][(wn * 32 + t * 16 + l16) * 64 + pc]);
      }
#pragma unroll
      for (int tm = 0; tm < 2; ++tm)
#pragma unroll
        for (int tn = 0; tn < 2; ++tn)
          acc[tm][tn] = __builtin_amdgcn_mfma_f32_16x16x32_bf16(af[tm], bf[tn], acc[tm][tn], 0, 0, 0);
    }
  }

  float* ob = out + (size_t)b * S_ * DV;
#pragma unroll
  for (int tm = 0; tm < 2; ++tm) {
    int rowb = m0 + wm * 32 + tm * 16 + quad * 4;
    float inv[4];
#pragma unroll
    for (int i = 0; i < 4; ++i) inv[i] = 1.0f / rowsum[b * S_ + rowb + i];
#pragma unroll
    for (int tn = 0; tn < 2; ++tn) {
      int col = n0 + wn * 32 + tn * 16 + l16;
      f32x4 a = acc[tm][tn];
      ob[(size_t)(rowb + 0) * DV + col] = a.x * inv[0];
      ob[(size_t)(rowb + 1) * DV + col] = a.y * inv[1];
      ob[(size_t)(rowb + 2) * DV + col] = a.z * inv[2];
      ob[(size_t)(rowb + 3) * DV + col] = a.w * inv[3];
    }
  }
}

extern "C" void kernel_launch(void* const* d_in, const int* in_sizes, int n_in,
                              void* d_out, int out_size, void* d_ws, size_t ws_size,
                              hipStream_t stream) {
  const float* x  = (const float*)d_in[0];
  const float* Wq = (const float*)d_in[1];
  const float* bq = (const float*)d_in[2];
  const float* Wk = (const float*)d_in[3];
  const float* bk = (const float*)d_in[4];
  const float* Wv = (const float*)d_in[5];
  const float* bv = (const float*)d_in[6];
  float* out = (float*)d_out;

  char* ws = (char*)d_ws;
  unsigned short* xb  = (unsigned short*)(ws);                         // 16 MB: x bf16
  unsigned short* wqt = (unsigned short*)(ws + 16777216);              // 1 MB each: W^T bf16
  unsigned short* wkt = (unsigned short*)(ws + 16777216 + 1048576);
  unsigned short* wvt = (unsigned short*)(ws + 16777216 + 2097152);
  unsigned short* qo  = (unsigned short*)(ws + 19922944);              // 8 MB: q bf16 (pre-scaled)
  unsigned short* ko  = (unsigned short*)(ws + 19922944 + 8388608);    // 8 MB: k bf16
  unsigned short* vto = (unsigned short*)(ws + 19922944 + 16777216);   // 8 MB: v^T bf16
  unsigned short* sp  = (unsigned short*)(ws + 45088768);              // 32 MB: e^S bf16
  float* rowsum       = (float*)(ws + 45088768 + 33554432);            // 32 KB

  dim3 gc(16, 32, 11);   // z<3: W^T transpose-convert; z>=3: x fp32->bf16
  conv_all_kernel<<<gc, 256, 0, stream>>>(x, Wq, Wk, Wv, xb, wqt, wkt, wvt, rowsum);
  qkv_dma_kernel<<<768, 256, 0, stream>>>(xb, wqt, wkt, wvt, bq, bk, bv, qo, ko, vto);
  s_exp_kernel<<<256, 512, 0, stream>>>(qo, ko, sp, rowsum);
  pv_kernel<<<1024, 256, 0, stream>>>(sp, vto, rowsum, out);
}